// Round 1
// baseline (218.916 us; speedup 1.0000x reference)
//
#include <hip/hip_runtime.h>

typedef _Float16 f16;
typedef _Float16 f16x8 __attribute__((ext_vector_type(8)));
typedef float f32x4 __attribute__((ext_vector_type(4)));

#define NEGV (-1e30f)

// ---------------- transpose / pack kernels ----------------

// x (B, D=1024, N=2048) f32  ->  xt (B, N, D) f16
__global__ __launch_bounds__(256) void transpose_x_kernel(const float* __restrict__ x,
                                                          f16* __restrict__ xt)
{
  __shared__ float t[32][33];
  int tx = threadIdx.x, ty = threadIdx.y;
  int n0 = blockIdx.x * 32, d0 = blockIdx.y * 32, b = blockIdx.z;
  const float* xb = x + (size_t)b * 1024 * 2048;
#pragma unroll
  for (int i = 0; i < 4; ++i)
    t[ty + 8 * i][tx] = xb[(size_t)(d0 + ty + 8 * i) * 2048 + n0 + tx];
  __syncthreads();
  f16* xtb = xt + (size_t)b * 2048 * 1024;
#pragma unroll
  for (int i = 0; i < 4; ++i)
    xtb[(size_t)(n0 + ty + 8 * i) * 1024 + d0 + tx] = (f16)t[tx][ty + 8 * i];
}

// Wq/Wk/Wv (H=16, D=1024, Da=64) f32 -> WqkvT (3072, 1024) f16
// row r = m*1024 + h*64 + e, col d:  WqkvT[r][d] = W_m[h][d][e]
__global__ __launch_bounds__(256) void pack_wqkv_kernel(const float* __restrict__ Wq,
                                                        const float* __restrict__ Wk,
                                                        const float* __restrict__ Wv,
                                                        f16* __restrict__ WT)
{
  __shared__ float t[32][33];
  int tx = threadIdx.x, ty = threadIdx.y;
  int d0 = blockIdx.x * 32, e0 = blockIdx.y * 32;
  int m = blockIdx.z >> 4, h = blockIdx.z & 15;
  const float* W = (m == 0) ? Wq : (m == 1) ? Wk : Wv;
  W += (size_t)h * 1024 * 64;
#pragma unroll
  for (int i = 0; i < 4; ++i)
    t[ty + 8 * i][tx] = W[(size_t)(d0 + ty + 8 * i) * 64 + e0 + tx];
  __syncthreads();
#pragma unroll
  for (int i = 0; i < 4; ++i)
    WT[(size_t)(m * 1024 + h * 64 + e0 + ty + 8 * i) * 1024 + d0 + tx] = (f16)t[tx][ty + 8 * i];
}

// Wo (1024,1024) f32 -> WoT (1024,1024) f16, WoT[m][k] = Wo[k][m]
__global__ __launch_bounds__(256) void pack_wo_kernel(const float* __restrict__ Wo,
                                                      f16* __restrict__ WoT)
{
  __shared__ float t[32][33];
  int tx = threadIdx.x, ty = threadIdx.y;
  int m0 = blockIdx.x * 32, k0 = blockIdx.y * 32;
#pragma unroll
  for (int i = 0; i < 4; ++i)
    t[ty + 8 * i][tx] = Wo[(size_t)(k0 + ty + 8 * i) * 1024 + m0 + tx];
  __syncthreads();
#pragma unroll
  for (int i = 0; i < 4; ++i)
    WoT[(size_t)(m0 + ty + 8 * i) * 1024 + k0 + tx] = (f16)t[tx][ty + 8 * i];
}

// ---------------- 128x128 f16 MFMA GEMM ----------------
// C[row][col] = sum_k A[row][k] * Bt[col][k]
// A: M x K row-major f16 (K-contiguous); Bt: N x K row-major f16.
// Epilogue: Ch != nullptr -> f16 store row-major with ld = ldc
//           else            f32 store row-major with ld = ldc (used for (B,D,N) output)
__global__ __launch_bounds__(256) void gemm_f16_kernel(
    const f16* __restrict__ A, const f16* __restrict__ Bt,
    int K, int ldc, long bstride, long cstride,
    f16* __restrict__ Ch, float* __restrict__ Cf)
{
  __shared__ __align__(16) f16 As[128 * 40];
  __shared__ __align__(16) f16 Bs[128 * 40];
  int tid = threadIdx.x;
  int lane = tid & 63, wv = tid >> 6, g = lane >> 4, r = lane & 15;
  int wr = wv >> 1, wc = wv & 1;
  size_t row0 = (size_t)blockIdx.y * 128;
  size_t col0 = (size_t)blockIdx.x * 128;
  Bt += (size_t)blockIdx.z * (size_t)bstride;

  int sr = tid >> 2;          // 0..63 staging row
  int ss = (tid & 3) * 8;     // staging k-offset (halves)

  f32x4 acc[4][4];
#pragma unroll
  for (int m = 0; m < 4; ++m)
#pragma unroll
    for (int n = 0; n < 4; ++n)
      acc[m][n] = (f32x4){0.f, 0.f, 0.f, 0.f};

  const f16* Ap = A + (row0 + sr) * (size_t)K + ss;
  const f16* Bp = Bt + (col0 + sr) * (size_t)K + ss;

  for (int k0 = 0; k0 < K; k0 += 32) {
    f16x8 a0 = *(const f16x8*)(Ap + k0);
    f16x8 a1 = *(const f16x8*)(Ap + 64 * (size_t)K + k0);
    f16x8 b0 = *(const f16x8*)(Bp + k0);
    f16x8 b1 = *(const f16x8*)(Bp + 64 * (size_t)K + k0);
    __syncthreads();
    *(f16x8*)&As[(sr) * 40 + ss] = a0;
    *(f16x8*)&As[(sr + 64) * 40 + ss] = a1;
    *(f16x8*)&Bs[(sr) * 40 + ss] = b0;
    *(f16x8*)&Bs[(sr + 64) * 40 + ss] = b1;
    __syncthreads();
    f16x8 af[4], bf[4];
#pragma unroll
    for (int m = 0; m < 4; ++m)
      af[m] = *(const f16x8*)&As[(wr * 64 + m * 16 + r) * 40 + g * 8];
#pragma unroll
    for (int n = 0; n < 4; ++n)
      bf[n] = *(const f16x8*)&Bs[(wc * 64 + n * 16 + r) * 40 + g * 8];
#pragma unroll
    for (int m = 0; m < 4; ++m)
#pragma unroll
      for (int n = 0; n < 4; ++n)
        acc[m][n] = __builtin_amdgcn_mfma_f32_16x16x32_f16(af[m], bf[n], acc[m][n], 0, 0, 0);
  }

  if (Ch) {
    Ch += (size_t)blockIdx.z * (size_t)cstride;
#pragma unroll
    for (int m = 0; m < 4; ++m)
#pragma unroll
      for (int n = 0; n < 4; ++n)
#pragma unroll
        for (int q = 0; q < 4; ++q)
          Ch[(row0 + wr * 64 + m * 16 + g * 4 + q) * (size_t)ldc +
             col0 + wc * 64 + n * 16 + r] = (f16)acc[m][n][q];
  } else {
    Cf += (size_t)blockIdx.z * (size_t)cstride;
#pragma unroll
    for (int m = 0; m < 4; ++m)
#pragma unroll
      for (int n = 0; n < 4; ++n)
#pragma unroll
        for (int q = 0; q < 4; ++q)
          Cf[(row0 + wr * 64 + m * 16 + g * 4 + q) * (size_t)ldc +
             col0 + wc * 64 + n * 16 + r] = acc[m][n][q];
  }
}

// ---------------- flash attention ----------------
// qkv: (B*N, 3072) f16, cols = [q | k | v] each 1024 with per-head offset h*64
// head out: (B*N, 1024) f16
// 4 waves, each owns 16 q-rows (QBLK=64); K/V tiles of 64 rows.
__global__ __launch_bounds__(256) void attn_kernel(const f16* __restrict__ qkv,
                                                   const float* __restrict__ mask,
                                                   f16* __restrict__ head)
{
  const int LDQ = 3072;
  const int LDS = 72;   // padded LDS row stride in halves (16B-aligned rows)
  __shared__ __align__(16) f16 Ks[64 * 72];
  __shared__ __align__(16) f16 Vt[64 * 72];     // transposed V: Vt[e][kk'] (kk block-swizzled)
  __shared__ __align__(16) f16 Ps[4][16 * 72];  // per-wave P tile

  int tid = threadIdx.x;
  int w = tid >> 6, lane = tid & 63, g = lane >> 4, r = lane & 15;
  int b = blockIdx.y >> 4, h = blockIdx.y & 15;
  int qt = blockIdx.x;
  const float* maskb = mask + b * 2048;

  // Q fragments (A-operand): row = qt*64 + w*16 + r, k-slots e = g*8+j (+32)
  int qrow = qt * 64 + w * 16 + r;
  const f16* qp = qkv + ((size_t)(b * 2048 + qrow)) * LDQ + h * 64;
  f16x8 aq0 = *(const f16x8*)(qp + g * 8);
  f16x8 aq1 = *(const f16x8*)(qp + 32 + g * 8);

  f32x4 o[4];
#pragma unroll
  for (int i = 0; i < 4; ++i) o[i] = (f32x4){0.f, 0.f, 0.f, 0.f};
  float mrun[4] = {-INFINITY, -INFINITY, -INFINITY, -INFINITY};
  float lrun[4] = {0.f, 0.f, 0.f, 0.f};

  int srow = tid >> 3;   // 0..31 (kv row within half-tile)
  int sseg = tid & 7;    // 16B segment within 128B row
  // swizzled Vt columns for this thread's two kv rows
  int c0 = ((((srow)      >> 3) ^ sseg) << 3) | (srow & 7);
  int c1 = ((((srow + 32) >> 3) ^ sseg) << 3) | (srow & 7);

  for (int kt = 0; kt < 32; ++kt) {
    const f16* kbase = qkv + ((size_t)(b * 2048 + kt * 64)) * LDQ + 1024 + h * 64;
    const f16* vbase = kbase + 1024;
    f16x8 kv0 = *(const f16x8*)(kbase + (size_t)srow * LDQ + sseg * 8);
    f16x8 kv1 = *(const f16x8*)(kbase + (size_t)(srow + 32) * LDQ + sseg * 8);
    f16x8 vv0 = *(const f16x8*)(vbase + (size_t)srow * LDQ + sseg * 8);
    f16x8 vv1 = *(const f16x8*)(vbase + (size_t)(srow + 32) * LDQ + sseg * 8);
    __syncthreads();  // prior compute done reading LDS
    *(f16x8*)&Ks[srow * LDS + sseg * 8] = kv0;
    *(f16x8*)&Ks[(srow + 32) * LDS + sseg * 8] = kv1;
#pragma unroll
    for (int j = 0; j < 8; ++j) {
      int e = sseg * 8 + j;
      Vt[e * LDS + c0] = vv0[j];
      Vt[e * LDS + c1] = vv1[j];
    }
    __syncthreads();  // staging visible

    // S = Q K^T (raw)
    f32x4 s[4];
#pragma unroll
    for (int c = 0; c < 4; ++c) {
      f16x8 bk0 = *(const f16x8*)&Ks[(c * 16 + r) * LDS + g * 8];
      f16x8 bk1 = *(const f16x8*)&Ks[(c * 16 + r) * LDS + 32 + g * 8];
      f32x4 z = (f32x4){0.f, 0.f, 0.f, 0.f};
      z = __builtin_amdgcn_mfma_f32_16x16x32_f16(aq0, bk0, z, 0, 0, 0);
      z = __builtin_amdgcn_mfma_f32_16x16x32_f16(aq1, bk1, z, 0, 0, 0);
      s[c] = z;
    }
    // scale + column mask:  s*scale*hm + (1-hm)*NEG
#pragma unroll
    for (int c = 0; c < 4; ++c) {
      float hm = maskb[kt * 64 + c * 16 + r];
      float mul = 0.125f * hm;
      float addv = (1.0f - hm) * NEGV;
#pragma unroll
      for (int q = 0; q < 4; ++q)
        s[c][q] = s[c][q] * mul + addv;
    }
    // online softmax: row stats across the 16-lane group (cols) per reg (row)
    float mnew[4], resc[4];
#pragma unroll
    for (int q = 0; q < 4; ++q) {
      float mx = fmaxf(fmaxf(s[0][q], s[1][q]), fmaxf(s[2][q], s[3][q]));
      mx = fmaxf(mx, __shfl_xor(mx, 1));
      mx = fmaxf(mx, __shfl_xor(mx, 2));
      mx = fmaxf(mx, __shfl_xor(mx, 4));
      mx = fmaxf(mx, __shfl_xor(mx, 8));
      float mn = fmaxf(mrun[q], mx);
      mnew[q] = mn;
      resc[q] = __expf(mrun[q] - mn);
      mrun[q] = mn;
    }
#pragma unroll
    for (int q = 0; q < 4; ++q) {
      float sum = 0.f;
      int prow = g * 4 + q;
#pragma unroll
      for (int c = 0; c < 4; ++c) {
        float p = __expf(s[c][q] - mnew[q]);
        sum += p;
        Ps[w][prow * LDS + c * 16 + r] = (f16)p;
      }
      sum += __shfl_xor(sum, 1);
      sum += __shfl_xor(sum, 2);
      sum += __shfl_xor(sum, 4);
      sum += __shfl_xor(sum, 8);
      lrun[q] = lrun[q] * resc[q] + sum;
#pragma unroll
      for (int ef = 0; ef < 4; ++ef) o[ef][q] *= resc[q];
    }
    __syncthreads();  // order Ps writes before same-wave reads (and keep waves aligned)

    // O += P V
    f16x8 pa0 = *(const f16x8*)&Ps[w][r * LDS + g * 8];
    f16x8 pa1 = *(const f16x8*)&Ps[w][r * LDS + 32 + g * 8];
#pragma unroll
    for (int ef = 0; ef < 4; ++ef) {
      int e = ef * 16 + r;
      int eb = (e >> 3) & 7;
      f16x8 vb0 = *(const f16x8*)&Vt[e * LDS + ((g ^ eb) << 3)];
      f16x8 vb1 = *(const f16x8*)&Vt[e * LDS + (((g + 4) ^ eb) << 3)];
      o[ef] = __builtin_amdgcn_mfma_f32_16x16x32_f16(pa0, vb0, o[ef], 0, 0, 0);
      o[ef] = __builtin_amdgcn_mfma_f32_16x16x32_f16(pa1, vb1, o[ef], 0, 0, 0);
    }
  }

  // epilogue: divide by l, apply row (v) mask, store f16 head
#pragma unroll
  for (int q = 0; q < 4; ++q) {
    int row = qt * 64 + w * 16 + g * 4 + q;
    float vm = maskb[row];
    float inv = vm / lrun[q];
    f16* hp = head + ((size_t)(b * 2048 + row)) * 1024 + h * 64;
#pragma unroll
    for (int ef = 0; ef < 4; ++ef)
      hp[ef * 16 + r] = (f16)(o[ef][q] * inv);
  }
}

// ---------------- launch ----------------
extern "C" void kernel_launch(void* const* d_in, const int* in_sizes, int n_in,
                              void* d_out, int out_size, void* d_ws, size_t ws_size,
                              hipStream_t stream)
{
  const float* x    = (const float*)d_in[0];
  const float* mask = (const float*)d_in[1];
  const float* Wq   = (const float*)d_in[2];
  const float* Wk   = (const float*)d_in[3];
  const float* Wv   = (const float*)d_in[4];
  const float* Wo   = (const float*)d_in[5];
  float* out = (float*)d_out;

  // workspace layout (40 MB total):
  //   [0,        8 MB)  xt (B*N,1024) f16 -> reused as head after gemm_qkv
  //   [8 MB,    14 MB)  WqkvT (3072,1024) f16
  //   [14 MB,   16 MB)  WoT (1024,1024) f16
  //   [16 MB,   40 MB)  qkv (B*N,3072) f16
  char* ws = (char*)d_ws;
  f16* xt_head = (f16*)(ws);
  f16* WqkvT   = (f16*)(ws + 8388608);
  f16* WoT     = (f16*)(ws + 14680064);
  f16* qkv     = (f16*)(ws + 16777216);

  transpose_x_kernel<<<dim3(64, 32, 2), dim3(32, 8), 0, stream>>>(x, xt_head);
  pack_wqkv_kernel<<<dim3(32, 2, 48), dim3(32, 8), 0, stream>>>(Wq, Wk, Wv, WqkvT);
  pack_wo_kernel<<<dim3(32, 32, 1), dim3(32, 8), 0, stream>>>(Wo, WoT);

  // qkv = xt @ WqkvT^T   (M=4096, N=3072, K=1024), f16 out
  gemm_f16_kernel<<<dim3(24, 32, 1), 256, 0, stream>>>(
      xt_head, WqkvT, 1024, 3072, 0, 0, qkv, nullptr);

  // head = attention(qkv)  (writes into xt region)
  attn_kernel<<<dim3(32, 32, 1), 256, 0, stream>>>(qkv, mask, xt_head);

  // out[b][d'][n] = sum_d WoT[d'][d] * head[b*N+n][d]  (M=1024, N=2048 per b)
  gemm_f16_kernel<<<dim3(16, 8, 2), 256, 0, stream>>>(
      WoT, xt_head, 1024, 2048, (long)2048 * 1024, (long)1024 * 2048, nullptr, out);
}